// Round 1
// baseline (109.675 us; speedup 1.0000x reference)
//
#include <hip/hip_runtime.h>

#define HH 1024
#define WW 1024
#define KK 9
#define PADK 4
#define TS 16
#define TILE 24  // TS + 2*PADK

// One thread per output pixel. 16x16 block stages a 24x24 float4 unet tile in
// LDS (reflect-padded), then each thread streams its 81 per-pixel weights from
// cnn_out (contiguous 324 B -> 20x dwordx4 + 1 dword) and accumulates 81 taps
// x 3 channels in registers. Memory-bound on cnn_out (340 MB).
__global__ __launch_bounds__(256) void denoiser_kpn(
    const float* __restrict__ unet, const float* __restrict__ cnn,
    float* __restrict__ out) {
  // +1 float4 row pad: row stride = 100 dwords = 4 banks mod 32 ->
  // (ty+tx) mod 8 bank-group spread -> conflict-free ds_read_b128.
  __shared__ float4 tile[TILE][TILE + 1];
  const int tid = threadIdx.x;
  const int tx = tid & 15;
  const int ty = tid >> 4;
  const int bx = blockIdx.x;
  const int by = blockIdx.y;
  const int y0 = by * TS - PADK;
  const int x0 = bx * TS - PADK;

  // Stage 24x24 reflect-padded pixels, 576 entries over 256 threads.
  for (int idx = tid; idx < TILE * TILE; idx += 256) {
    const int i = idx / TILE;
    const int j = idx - i * TILE;
    int gy = y0 + i;
    gy = gy < 0 ? -gy : (gy >= HH ? 2 * HH - 2 - gy : gy);
    int gx = x0 + j;
    gx = gx < 0 ? -gx : (gx >= WW ? 2 * WW - 2 - gx : gx);
    const float* p = unet + (gy * WW + gx) * 3;
    tile[i][j] = make_float4(p[0], p[1], p[2], 0.0f);
  }
  __syncthreads();

  const int py = by * TS + ty;
  const int px = bx * TS + tx;
  const float* wp = cnn + (size_t)(py * WW + px) * 81;

  // Load all 81 weights into registers (20 x 16B unaligned-vector + 1 scalar).
  float wreg[81];
#pragma unroll
  for (int t = 0; t < 20; ++t) {
    float4 v;
    __builtin_memcpy(&v, wp + 4 * t, 16);
    wreg[4 * t + 0] = v.x;
    wreg[4 * t + 1] = v.y;
    wreg[4 * t + 2] = v.z;
    wreg[4 * t + 3] = v.w;
  }
  wreg[80] = wp[80];

  float ax = 0.0f, ay = 0.0f, az = 0.0f;
#pragma unroll
  for (int k = 0; k < 81; ++k) {
    const int i = k / KK;
    const int j = k - i * KK;
    const float4 p = tile[ty + i][tx + j];
    const float w = wreg[k];
    ax = fmaf(w, p.x, ax);
    ay = fmaf(w, p.y, ay);
    az = fmaf(w, p.z, az);
  }

  float* o = out + (size_t)(py * WW + px) * 3;
  o[0] = ax;
  o[1] = ay;
  o[2] = az;
}

extern "C" void kernel_launch(void* const* d_in, const int* in_sizes, int n_in,
                              void* d_out, int out_size, void* d_ws, size_t ws_size,
                              hipStream_t stream) {
  const float* unet = (const float*)d_in[0];  // [1024,1024,3] f32
  const float* cnn = (const float*)d_in[1];   // [1024,1024,81] f32
  float* out = (float*)d_out;                 // [1024,1024,3] f32
  dim3 grid(WW / TS, HH / TS);
  dim3 block(256);
  denoiser_kpn<<<grid, block, 0, stream>>>(unet, cnn, out);
}

// Round 2
// 91.737 us; speedup vs baseline: 1.1955x; 1.1955x over previous
//
#include <hip/hip_runtime.h>

#define HH 1024
#define WW 1024
#define KK 9
#define PADK 4
#define TS 16
#define TILE 24  // TS + 2*PADK
#define KC 27    // k-chunk (81 = 3*27)
#define NCH 3

// One thread per output pixel (16x16 block). unet staged as 24x24 float4 LDS
// tile (reflect-padded). Per-pixel 81 weights staged through LDS in 3 chunks
// of 27 via global_load_lds: LDS dst is linear g = tid + 256*i (wave-uniform
// base + lane*4, the DMA requirement), global src is pixel g/27, weight g%27
// -> every staging instruction is lane-contiguous (coalesced), killing the
// stride-324 address divergence that made round-1 TA/L1-transaction-bound.
__global__ __launch_bounds__(256) void denoiser_kpn(
    const float* __restrict__ unet, const float* __restrict__ cnn,
    float* __restrict__ out) {
  __shared__ float4 tile[TILE][TILE + 1];  // +1 pad: conflict-free b128 reads
  __shared__ float wlds[256 * KC];         // [pixel][27], stride 27 (odd) -> 2-way max

  const int tid = threadIdx.x;
  const int tx = tid & 15;
  const int ty = tid >> 4;
  const int bx = blockIdx.x;
  const int by = blockIdx.y;
  const int y0 = by * TS - PADK;
  const int x0 = bx * TS - PADK;

  // Stage 24x24 reflect-padded unet pixels (L3-resident after first touch).
  for (int idx = tid; idx < TILE * TILE; idx += 256) {
    const int i = idx / TILE;
    const int j = idx - i * TILE;
    int gy = y0 + i;
    gy = gy < 0 ? -gy : (gy >= HH ? 2 * HH - 2 - gy : gy);
    int gx = x0 + j;
    gx = gx < 0 ? -gx : (gx >= WW ? 2 * WW - 2 - gx : gx);
    const float* p = unet + (gy * WW + gx) * 3;
    tile[i][j] = make_float4(p[0], p[1], p[2], 0.0f);
  }

  float ax = 0.0f, ay = 0.0f, az = 0.0f;

#pragma unroll
  for (int c = 0; c < NCH; ++c) {
    if (c > 0) __syncthreads();  // chunk c-1 fully consumed before overwrite

    // Stage chunk c: 256*27 dwords, linear in LDS, coalesced from global.
#pragma unroll
    for (int i = 0; i < KC; ++i) {
      const int g = tid + 256 * i;
      const int p = g / KC;        // pixel index in block [0,256)
      const int dk = g - p * KC;   // weight offset within chunk
      const int pr = p >> 4;
      const int pc = p & 15;
      const float* src =
          cnn + ((size_t)((by * TS + pr) * WW + (bx * TS + pc))) * 81 + c * KC + dk;
      __builtin_amdgcn_global_load_lds(
          (const __attribute__((address_space(1))) unsigned int*)src,
          (__attribute__((address_space(3))) unsigned int*)&wlds[g], 4, 0, 0);
    }
    __syncthreads();  // barrier drains vmcnt (DMA) + lgkm (tile writes, c==0)

    // Compute chunk c: 27 taps x 3 channels.
#pragma unroll
    for (int dk = 0; dk < KC; ++dk) {
      const int k = c * KC + dk;   // compile-time under full unroll
      const int ki = k / KK;
      const int kj = k - ki * KK;
      const float w = wlds[tid * KC + dk];
      const float4 pv = tile[ty + ki][tx + kj];
      ax = fmaf(w, pv.x, ax);
      ay = fmaf(w, pv.y, ay);
      az = fmaf(w, pv.z, az);
    }
  }

  const int py = by * TS + ty;
  const int px = bx * TS + tx;
  float* o = out + (size_t)(py * WW + px) * 3;
  o[0] = ax;
  o[1] = ay;
  o[2] = az;
}

extern "C" void kernel_launch(void* const* d_in, const int* in_sizes, int n_in,
                              void* d_out, int out_size, void* d_ws, size_t ws_size,
                              hipStream_t stream) {
  const float* unet = (const float*)d_in[0];  // [1024,1024,3] f32
  const float* cnn = (const float*)d_in[1];   // [1024,1024,81] f32
  float* out = (float*)d_out;                 // [1024,1024,3] f32
  dim3 grid(WW / TS, HH / TS);
  dim3 block(256);
  denoiser_kpn<<<grid, block, 0, stream>>>(unet, cnn, out);
}